// Round 11
// baseline (40.918 us; speedup 1.0000x reference)
//
#include <hip/hip_runtime.h>
#include <hip/hip_bf16.h>

typedef __attribute__((ext_vector_type(4))) float f32x4;
typedef __attribute__((ext_vector_type(8))) short bf16x8;

#define N_NEI 64
#define D_IN  128
#define D_HID 128

union BF8 { bf16x8 v; __hip_bfloat162 h[4]; unsigned u[4]; };

__device__ __forceinline__ bf16x8 pack8(const float4& a, const float4& b) {
  BF8 r;
  r.h[0] = __float22bfloat162_rn(float2{a.x, a.y});
  r.h[1] = __float22bfloat162_rn(float2{a.z, a.w});
  r.h[2] = __float22bfloat162_rn(float2{b.x, b.y});
  r.h[3] = __float22bfloat162_rn(float2{b.z, b.w});
  return r.v;
}

// One dual-M-tile step (R8's proven inner loop, unchanged): 32 neighbor rows,
// every B-fragment LDS read feeds two MFMAs; acc in 2 passes of 4 (anti-spill).
__device__ __forceinline__ void k1_iter(const float4 (&pf)[16],
                                        const unsigned short* Wl,
                                        const float (&bml)[8], float (&pmax)[8],
                                        int lr, int lg) {
  bf16x8 afA[4], afB[4];
  float rsA = 0.f, rsB = 0.f;
  #pragma unroll
  for (int ks = 0; ks < 4; ++ks) {
    float4 a0 = pf[2 * ks],     a1 = pf[2 * ks + 1];
    float4 b0 = pf[8 + 2 * ks], b1 = pf[9 + 2 * ks];
    rsA += a0.x + a0.y + a0.z + a0.w + a1.x + a1.y + a1.z + a1.w;
    rsB += b0.x + b0.y + b0.z + b0.w + b1.x + b1.y + b1.z + b1.w;
    afA[ks] = pack8(a0, a1);
    afB[ks] = pack8(b0, b1);
  }
  rsA += __shfl_xor(rsA, 16); rsA += __shfl_xor(rsA, 32);
  rsB += __shfl_xor(rsB, 16); rsB += __shfl_xor(rsB, 32);
  unsigned maskA = (unsigned)(__ballot(rsA == 0.0f) & 0xFFFFull);
  unsigned maskB = (unsigned)(__ballot(rsB == 0.0f) & 0xFFFFull);

  #pragma unroll 1
  for (int p = 0; p < 2; ++p) {
    f32x4 accA[4], accB[4];
    #pragma unroll
    for (int tt = 0; tt < 4; ++tt) {
      accA[tt] = (f32x4){0.f, 0.f, 0.f, 0.f};
      accB[tt] = (f32x4){0.f, 0.f, 0.f, 0.f};
    }
    #pragma unroll
    for (int tt = 0; tt < 4; ++tt) {
      #pragma unroll
      for (int ks = 0; ks < 4; ++ks) {
        int jr = (p * 4 + tt) * 16 + lr;
        int d0 = ks * 32 + lg * 8;
        bf16x8 bf = *(const bf16x8*)((const char*)Wl + jr * 256 + ((d0 * 2) ^ ((jr & 7) << 4)));
        accA[tt] = __builtin_amdgcn_mfma_f32_16x16x32_bf16(afA[ks], bf, accA[tt], 0, 0, 0);
        accB[tt] = __builtin_amdgcn_mfma_f32_16x16x32_bf16(afB[ks], bf, accB[tt], 0, 0, 0);
      }
    }
    #pragma unroll
    for (int tt = 0; tt < 4; ++tt) {
      #pragma unroll
      for (int r = 0; r < 4; ++r) {
        int row = lg * 4 + r;            // D-layout: row = (l>>4)*4 + reg
        float vA = fmaxf(accA[tt][r] + bml[p * 4 + tt], 0.f);
        float vB = fmaxf(accB[tt][r] + bml[p * 4 + tt], 0.f);
        if ((maskA >> row) & 1u) vA = 0.f;
        if ((maskB >> row) & 1u) vB = 0.f;
        pmax[p * 4 + tt] = fmaxf(pmax[p * 4 + tt], fmaxf(vA, vB));
      }
    }
  }
}

// Kernel 1: pooled[b][j] = max_n relu(neigh[b,n,:]·W_mlp[j,:] + b_mlp[j]), masked rows -> 0.
// Round-10 diagnosis: arch-VGPR budget ~60 => compiler sinks loads to their
// uses and issues them in dribbles, serially exposing full memory latency
// (explains the ~10x gap between cycle model and measured time, and why all
// scheduling tweaks were noise). Fix: BATCHED PINNED LOAD ISSUE —
// sched_barrier(0) after each load batch forces wide issue + wide allocation:
//   batch 1: all 16 W float4 (L2-hot)
//   batch 2: ALL 32 neighbor float4 for this wave's 64 rows (pfA+pfB ping-pong)
//   then W convert/stage runs while pf flies; main loop has ZERO loads.
__global__ __launch_bounds__(256, 2)
void k1_pool(const float* __restrict__ neigh, const float* __restrict__ Wmlp,
             const float* __restrict__ bmlp, unsigned short* __restrict__ pooled) {
  __shared__ unsigned short Wl[D_HID * D_IN];  // 32KB bf16, row j = 256B, XOR-swizzled
  __shared__ float pscr[4][D_HID];             // per-wave epilogue scratch

  const int tid = threadIdx.x;
  const int l = tid & 63;
  const int w = tid >> 6;
  const int lr = l & 15;   // A row-in-tile / B col-in-tile
  const int lg = l >> 4;   // k-group

  const int b = blockIdx.x * 4 + w;     // this wave's batch row
  const float* rowbase = neigh + (size_t)b * N_NEI * D_IN;

  // batch 1: W_mlp loads (L2-hot after first blocks), all 16 in flight
  const float4* W4 = (const float4*)Wmlp;
  float4 wtA[8], wtB[8];
  #pragma unroll
  for (int i = 0; i < 8; ++i) {
    int f8 = i * 256 + tid;             // 8-float chunk id
    wtA[i] = W4[f8 * 2];
    wtB[i] = W4[f8 * 2 + 1];
  }
  __builtin_amdgcn_sched_barrier(0);

  // batch 2: ALL neighbor fragments for this wave (64 rows, 32 float4)
  float4 pfA[16], pfB[16];
  {
    const float* r0 = rowbase + (size_t)lr * D_IN + lg * 8;
    #pragma unroll
    for (int ks = 0; ks < 4; ++ks) {
      pfA[2 * ks]     = *(const float4*)(r0 + ks * 32);
      pfA[2 * ks + 1] = *(const float4*)(r0 + ks * 32 + 4);
      pfA[8 + 2 * ks] = *(const float4*)(r0 + 16 * D_IN + ks * 32);
      pfA[9 + 2 * ks] = *(const float4*)(r0 + 16 * D_IN + ks * 32 + 4);
      pfB[2 * ks]     = *(const float4*)(r0 + 32 * D_IN + ks * 32);
      pfB[2 * ks + 1] = *(const float4*)(r0 + 32 * D_IN + ks * 32 + 4);
      pfB[8 + 2 * ks] = *(const float4*)(r0 + 48 * D_IN + ks * 32);
      pfB[9 + 2 * ks] = *(const float4*)(r0 + 48 * D_IN + ks * 32 + 4);
    }
  }
  __builtin_amdgcn_sched_barrier(0);

  // convert + stage W while pf is in flight (consumes wtA/wtB only)
  #pragma unroll
  for (int i = 0; i < 8; ++i) {
    int f8 = i * 256 + tid;
    int j  = f8 >> 4;                   // row 0..127
    int d0 = (f8 & 15) * 8;             // col start
    int byte = j * 256 + ((d0 * 2) ^ ((j & 7) << 4));
    *(bf16x8*)((char*)Wl + byte) = pack8(wtA[i], wtB[i]);
  }

  float bml[8];
  #pragma unroll
  for (int t = 0; t < 8; ++t) bml[t] = bmlp[t * 16 + lr];

  __syncthreads();   // drains staging; pf arrives under the W-processing window

  float pmax[8];
  #pragma unroll
  for (int t = 0; t < 8; ++t) pmax[t] = 0.f;  // exact: masked rows are 0, relu >= 0

  k1_iter(pfA, Wl, bml, pmax, lr, lg);   // neighbors  0..31
  k1_iter(pfB, Wl, bml, pmax, lr, lg);   // neighbors 32..63

  // cross-lane-group max (rows live in lg groups)
  #pragma unroll
  for (int t = 0; t < 8; ++t) {
    pmax[t] = fmaxf(pmax[t], __shfl_xor(pmax[t], 16));
    pmax[t] = fmaxf(pmax[t], __shfl_xor(pmax[t], 32));
  }

  // epilogue: transpose via per-wave LDS scratch, packed bf16x2 store (256B/wave)
  if (l < 16) {
    #pragma unroll
    for (int t = 0; t < 8; ++t) pscr[w][t * 16 + l] = pmax[t];
  }
  __syncthreads();   // once per kernel; also orders pscr write->read
  float2 pv = *(const float2*)&pscr[w][2 * l];
  __hip_bfloat162 h2 = __float22bfloat162_rn(pv);
  ((unsigned*)(pooled + (size_t)b * D_HID))[l] = *(unsigned*)&h2;
}

// Kernel 2: out[b][j] = relu([input|pooled][b,:]·W_comb[j,:] + b_comb[j])
// Block = 64 rows x 64 cols, K = 256 (R8 structure) + batched pinned loads.
__global__ __launch_bounds__(256, 2)
void k2_comb(const float* __restrict__ inp, const unsigned short* __restrict__ pooled,
             const float* __restrict__ Wcomb, const float* __restrict__ bcomb,
             float* __restrict__ out) {
  __shared__ unsigned short Wl[64 * 256];  // 32KB: 64 output cols x K=256, row = 512B, swizzled

  const int tid = threadIdx.x;
  const int l = tid & 63;
  const int w = tid >> 6;
  const int mchunk = blockIdx.x >> 2;   // 64-row chunk, 0..63
  const int colq   = blockIdx.x & 3;    // 64-col quarter
  const int lr = l & 15;
  const int lg = l >> 4;

  const int row = mchunk * 64 + w * 16 + lr;

  // batch 1: A loads (input fp32 + pooled bf16)
  float4 a0[4], a1[4];
  #pragma unroll
  for (int ks = 0; ks < 4; ++ks) {
    const float* p = inp + (size_t)row * 128 + ks * 32 + lg * 8;
    a0[ks] = *(const float4*)p;
    a1[ks] = *(const float4*)(p + 4);
  }
  bf16x8 af[8];
  #pragma unroll
  for (int ks = 4; ks < 8; ++ks) {
    af[ks] = *(const bf16x8*)(pooled + (size_t)row * 128 + (ks - 4) * 32 + lg * 8);
  }
  __builtin_amdgcn_sched_barrier(0);

  // batch 2: W quarter loads, all 16 float4 in flight
  const float4* W4 = (const float4*)Wcomb;
  float4 wtA[8], wtB[8];
  #pragma unroll
  for (int i = 0; i < 8; ++i) {
    int c  = i * 256 + tid;             // 8-float chunk, 0..2047
    int jr = c >> 5;                    // 0..63
    int d0 = (c & 31) * 8;
    int gidx = ((colq * 64 + jr) * 256 + d0) >> 2;
    wtA[i] = W4[gidx];
    wtB[i] = W4[gidx + 1];
  }
  __builtin_amdgcn_sched_barrier(0);

  // convert + stage W
  #pragma unroll
  for (int i = 0; i < 8; ++i) {
    int c  = i * 256 + tid;
    int jr = c >> 5;
    int d0 = (c & 31) * 8;
    int byte = jr * 512 + ((d0 * 2) ^ ((jr & 7) << 4));
    *(bf16x8*)((char*)Wl + byte) = pack8(wtA[i], wtB[i]);
  }

  float bcl[4];
  #pragma unroll
  for (int t = 0; t < 4; ++t) bcl[t] = bcomb[colq * 64 + t * 16 + lr];

  #pragma unroll
  for (int ks = 0; ks < 4; ++ks) af[ks] = pack8(a0[ks], a1[ks]);

  __syncthreads();

  f32x4 acc[4];
  #pragma unroll
  for (int t = 0; t < 4; ++t) acc[t] = (f32x4){0.f, 0.f, 0.f, 0.f};
  #pragma unroll
  for (int t = 0; t < 4; ++t) {
    #pragma unroll
    for (int ks = 0; ks < 8; ++ks) {
      int jr = t * 16 + lr;
      int d0 = ks * 32 + lg * 8;
      bf16x8 bf = *(const bf16x8*)((const char*)Wl + jr * 512 + ((d0 * 2) ^ ((jr & 7) << 4)));
      acc[t] = __builtin_amdgcn_mfma_f32_16x16x32_bf16(af[ks], bf, acc[t], 0, 0, 0);
    }
  }

  #pragma unroll
  for (int t = 0; t < 4; ++t) {
    #pragma unroll
    for (int r = 0; r < 4; ++r) {
      int ro = mchunk * 64 + w * 16 + lg * 4 + r;
      int co = colq * 64 + t * 16 + lr;
      float v = acc[t][r] + bcl[t];
      out[(size_t)ro * 256 + co] = fmaxf(v, 0.f);
    }
  }
}

extern "C" void kernel_launch(void* const* d_in, const int* in_sizes, int n_in,
                              void* d_out, int out_size, void* d_ws, size_t ws_size,
                              hipStream_t stream) {
  const float* inp   = (const float*)d_in[0];
  const float* neigh = (const float*)d_in[1];
  const float* Wmlp  = (const float*)d_in[2];
  const float* bmlp  = (const float*)d_in[3];
  const float* Wcomb = (const float*)d_in[4];
  const float* bcomb = (const float*)d_in[5];
  float* out = (float*)d_out;
  unsigned short* pooled = (unsigned short*)d_ws;  // [4096][128] bf16, 1 MB

  k1_pool<<<1024, 256, 0, stream>>>(neigh, Wmlp, bmlp, pooled);
  k2_comb<<<256, 256, 0, stream>>>(inp, pooled, Wcomb, bcomb, out);
}